// Round 5
// baseline (389.438 us; speedup 1.0000x reference)
//
#include <hip/hip_runtime.h>
#include <hip/hip_bf16.h>
#include <stdint.h>

#define NTOK 8192   // B*T
#define DDIM 1024
#define LDIM 512
#define VCB  8192
#define MROWS 16384 // NTOK + VCB

typedef unsigned long long u64;
typedef unsigned short ushort_t;
typedef unsigned char u8;
typedef float f32x4 __attribute__((ext_vector_type(4)));
typedef short s16x8 __attribute__((ext_vector_type(8)));
typedef int i32x8 __attribute__((ext_vector_type(8)));

// ---- workspace layout (bytes) ----
#define OFF_AB     0ull                                   // 33.5 MB
#define OFF_QB     0ull                                   // alias (16.8 MB)
#define OFF_P      ((u64)MROWS * DDIM * 2)                // 16.8 MB
#define OFF_QF     (OFF_P + (u64)MROWS * LDIM * 2)        // 8.4 MB fp8
#define OFF_WT     (OFF_QF + (u64)MROWS * 512)            // 2 MB
#define OFF_B2     (OFF_WT + (u64)2 * LDIM * DDIM * 2)    // VCB fp32 (fp8-consistent)
#define OFF_B2B    (OFF_B2 + (u64)VCB * 4)                // VCB fp32 (bf16-consistent)
#define OFF_PART   (OFF_B2B + (u64)VCB * 4)               // NTOK*64 u32 = 2 MB
#define OFF_HIST   (OFF_PART + (u64)NTOK * 64 * 4)        // VCB int
#define OFF_PARTQ  (OFF_HIST + (u64)VCB * 4)              // NTOK fp32
#define OFF_PARTL  (OFF_PARTQ + (u64)NTOK * 4)            // NTOK fp32

__device__ __forceinline__ unsigned key_of(float f) {
  unsigned u = __float_as_uint(f);
  return (u & 0x80000000u) ? ~u : (u | 0x80000000u);
}

__device__ __forceinline__ ushort_t f2bf(float f) {
  unsigned u = __float_as_uint(f);
  unsigned r = (u + 0x7fffu + ((u >> 16) & 1u)) >> 16;
  return (ushort_t)r;
}
__device__ __forceinline__ float bf2f(unsigned b) {
  return __uint_as_float(b << 16);
}
__device__ __forceinline__ unsigned pkbf(float a, float b) {
  __hip_bfloat162 h = __float22bfloat162_rn(make_float2(a, b));
  unsigned r;
  __builtin_memcpy(&r, &h, 4);
  return r;
}

__device__ __forceinline__ void gload_lds16(const void* g, void* l) {
  __builtin_amdgcn_global_load_lds(
      (const __attribute__((address_space(1))) unsigned int*)g,
      (__attribute__((address_space(3))) unsigned int*)l, 16, 0, 0);
}

__device__ __forceinline__ f32x4 mfma16(s16x8 a, s16x8 b, f32x4 c) {
  return __builtin_amdgcn_mfma_f32_16x16x32_bf16(a, b, c, 0, 0, 0);
}
// MX-scaled fp8 MFMA, K=128, unit scales (E8M0 127 -> 2^0). FMT 0 = OCP e4m3.
__device__ __forceinline__ f32x4 mfma_mx(i32x8 a, i32x8 b, f32x4 c) {
  return __builtin_amdgcn_mfma_scale_f32_16x16x128_f8f6f4(
      a, b, c, 0, 0, 0, 0x7f7f7f7f, 0, 0x7f7f7f7f);
}

// fp8 byte -> f32, byte index must be literal: explicit dispatch
__device__ __forceinline__ float fp8_byte_f32_0(int w) { return __builtin_amdgcn_cvt_f32_fp8(w, 0); }
__device__ __forceinline__ float fp8_byte_f32_1(int w) { return __builtin_amdgcn_cvt_f32_fp8(w, 1); }
__device__ __forceinline__ float fp8_byte_f32_2(int w) { return __builtin_amdgcn_cvt_f32_fp8(w, 2); }
__device__ __forceinline__ float fp8_byte_f32_3(int w) { return __builtin_amdgcn_cvt_f32_fp8(w, 3); }

// ------ W transpose + bf16 cast: Wt[n][k] = W[k][n]; hist init folded -------
__global__ __launch_bounds__(256)
void k_wt(const float* __restrict__ Wi, const float* __restrict__ Wc,
          ushort_t* __restrict__ Wt, int* __restrict__ hist) {
  __shared__ float tile[32][33];
  const int tx = threadIdx.x, ty = threadIdx.y;
  const int t = ty * 32 + tx;
  const int lb = blockIdx.z * 512 + blockIdx.y * 32 + blockIdx.x;
  if (lb < 32) hist[lb * 256 + t] = 0;
  const float* W = blockIdx.z ? Wc : Wi;
  ushort_t* O = Wt + (blockIdx.z ? (size_t)LDIM * DDIM : 0);
  const int k0 = blockIdx.x * 32, n0 = blockIdx.y * 32;
#pragma unroll
  for (int i = 0; i < 4; ++i)
    tile[ty * 4 + i][tx] = W[(size_t)(k0 + ty * 4 + i) * LDIM + n0 + tx];
  __syncthreads();
#pragma unroll
  for (int i = 0; i < 4; ++i)
    O[(size_t)(n0 + ty * 4 + i) * DDIM + k0 + tx] = f2bf(tile[tx][ty * 4 + i]);
}

// ---------------- cast [x; codebook] fp32 -> Ab bf16 ----------------
__global__ __launch_bounds__(256)
void k_cast(const float* __restrict__ x, const float* __restrict__ cb,
            ushort_t* __restrict__ Ab) {
  size_t i = ((size_t)blockIdx.x * 256 + threadIdx.x) * 8;
  const size_t half = (size_t)NTOK * DDIM;
  const float* src = (i < half) ? (x + i) : (cb + (i - half));
  float4 a = *(const float4*)src;
  float4 b = *(const float4*)(src + 4);
  uint4 o = make_uint4(pkbf(a.x, a.y), pkbf(a.z, a.w),
                       pkbf(b.x, b.y), pkbf(b.z, b.w));
  *(uint4*)&Ab[i] = o;
}

// -------- latent GEMM (MFMA, BK=64): P = Ab @ Wt^T + b --------
// 128x128 tile, 16 K-iters of 64 bf16 (128B rows). 8-slot XOR swizzle
// slot^(row&7), both-sides involution, linear gload_lds dest.
__global__ __launch_bounds__(256)
void k_latent(const ushort_t* __restrict__ Ab, const ushort_t* __restrict__ Wt,
              const float* __restrict__ bi, const float* __restrict__ bc,
              ushort_t* __restrict__ Pb) {
  __shared__ __align__(16) u8 As[128 * 128];   // 16 KB
  __shared__ __align__(16) u8 Bs[128 * 128];   // 16 KB
  const int t = threadIdx.x;
  const int wave = t >> 6, lane = t & 63;
  const int col0 = blockIdx.x * 128;   // L index
  const int m0 = blockIdx.y * 128;     // row index in [0, MROWS)
  const bool isCode = (m0 >= NTOK);
  const u8* A = (const u8*)(Ab + (size_t)m0 * DDIM);
  const u8* W = (const u8*)(Wt + (isCode ? (size_t)LDIM * DDIM : 0) +
                            (size_t)col0 * DDIM);
  const float* bias = isCode ? bc : bi;

  // staging: wave w, instr p covers rows w*32+p*8..+8 (8 rows x 128B = 1KB)
  const int srow8 = lane >> 3;   // 0..7
  const int sslot = lane & 7;    // 16B slot within 128B row
  size_t go[4];
  int lwo[4];
#pragma unroll
  for (int p = 0; p < 4; ++p) {
    const int r = wave * 32 + p * 8 + srow8;
    go[p] = (size_t)r * 2048 + (size_t)((sslot ^ (r & 7)) << 4);
    lwo[p] = (wave * 32 + p * 8) * 128;
  }

  const int wm = wave >> 1, wn = wave & 1;
  const int m = lane & 15, q = lane >> 4;
  // bf16 16x16x32 A-frag: lane group q holds k=q*8..q*8+7 (16B). With BK=64,
  // k-subtile s in {0,1} -> slot = s*4+q of the 128B row, swizzled ^(fr&7).
  int roffA[4][2], roffB[4][2];
#pragma unroll
  for (int i = 0; i < 4; ++i) {
#pragma unroll
    for (int s = 0; s < 2; ++s) {
      int fr = wm * 64 + i * 16 + m;
      roffA[i][s] = fr * 128 + (((s * 4 + q) ^ (fr & 7)) << 4);
      fr = wn * 64 + i * 16 + m;
      roffB[i][s] = fr * 128 + (((s * 4 + q) ^ (fr & 7)) << 4);
    }
  }

  f32x4 acc[4][4];
#pragma unroll
  for (int i = 0; i < 4; ++i)
#pragma unroll
    for (int j = 0; j < 4; ++j) acc[i][j] = (f32x4)(0.f);

  for (int it = 0; it < DDIM / 64; ++it) {
    const size_t kb = (size_t)it * 128;
    __syncthreads();
#pragma unroll
    for (int p = 0; p < 4; ++p) gload_lds16(A + go[p] + kb, As + lwo[p]);
#pragma unroll
    for (int p = 0; p < 4; ++p) gload_lds16(W + go[p] + kb, Bs + lwo[p]);
    __syncthreads();
    s16x8 af[4][2], bfr[4][2];
#pragma unroll
    for (int i = 0; i < 4; ++i) {
      af[i][0] = *(const s16x8*)(As + roffA[i][0]);
      af[i][1] = *(const s16x8*)(As + roffA[i][1]);
    }
#pragma unroll
    for (int j = 0; j < 4; ++j) {
      bfr[j][0] = *(const s16x8*)(Bs + roffB[j][0]);
      bfr[j][1] = *(const s16x8*)(Bs + roffB[j][1]);
    }
#pragma unroll
    for (int s = 0; s < 2; ++s)
#pragma unroll
      for (int i = 0; i < 4; ++i)
#pragma unroll
        for (int j = 0; j < 4; ++j)
          acc[i][j] = mfma16(af[i][s], bfr[j][s], acc[i][j]);
  }

  float bv[4];
#pragma unroll
  for (int j = 0; j < 4; ++j) bv[j] = bias[col0 + wn * 64 + j * 16 + m];
#pragma unroll
  for (int i = 0; i < 4; ++i)
#pragma unroll
    for (int j = 0; j < 4; ++j) {
      int col = col0 + wn * 64 + j * 16 + m;
#pragma unroll
      for (int reg = 0; reg < 4; ++reg) {
        int row = m0 + wm * 64 + i * 16 + q * 4 + reg;
        Pb[(size_t)row * LDIM + col] = f2bf(acc[i][j][reg] + bv[j]);
      }
    }
}

// ------ row normalize: one wave per row, no LDS, no barriers ------
// lane l covers k = l*8 .. l*8+7 (linear). Writes Qf fp8 (8B), Qb bf16 (16B).
__global__ __launch_bounds__(256)
void k_rownorm(const ushort_t* __restrict__ P, u8* __restrict__ Qf,
               ushort_t* __restrict__ Qb, float* __restrict__ b2,
               float* __restrict__ b2b) {
  const int row = blockIdx.x * 4 + (threadIdx.x >> 6);
  const int l = threadIdx.x & 63;
  const uint4 pv = *(const uint4*)(P + (size_t)row * LDIM + l * 8);
  float v[8];
  v[0] = bf2f(pv.x & 0xffffu); v[1] = bf2f(pv.x >> 16);
  v[2] = bf2f(pv.y & 0xffffu); v[3] = bf2f(pv.y >> 16);
  v[4] = bf2f(pv.z & 0xffffu); v[5] = bf2f(pv.z >> 16);
  v[6] = bf2f(pv.w & 0xffffu); v[7] = bf2f(pv.w >> 16);
  float s = 0.f;
#pragma unroll
  for (int k = 0; k < 8; ++k) s = fmaf(v[k], v[k], s);
#pragma unroll
  for (int msk = 1; msk < 64; msk <<= 1) s += __shfl_xor(s, msk, 64);
  const float rs = (float)(1.0 / sqrt((double)s + 1e-12));
  float w[8];
#pragma unroll
  for (int k = 0; k < 8; ++k) w[k] = v[k] * rs;
  unsigned q0 = (unsigned)__builtin_amdgcn_cvt_pk_fp8_f32(w[0], w[1], 0, false);
  q0 = (unsigned)__builtin_amdgcn_cvt_pk_fp8_f32(w[2], w[3], (int)q0, true);
  unsigned q1 = (unsigned)__builtin_amdgcn_cvt_pk_fp8_f32(w[4], w[5], 0, false);
  q1 = (unsigned)__builtin_amdgcn_cvt_pk_fp8_f32(w[6], w[7], (int)q1, true);
  *(uint2*)(Qf + (size_t)row * 512 + l * 8) = make_uint2(q0, q1);
  uint4 qb = make_uint4(pkbf(w[0], w[1]), pkbf(w[2], w[3]),
                        pkbf(w[4], w[5]), pkbf(w[6], w[7]));
  *(uint4*)(Qb + (size_t)row * LDIM + l * 8) = qb;
  if (row >= NTOK) {
    float s8 = 0.f, sb = 0.f;
    {
      float f;
      f = fp8_byte_f32_0((int)q0); s8 = fmaf(f, f, s8);
      f = fp8_byte_f32_1((int)q0); s8 = fmaf(f, f, s8);
      f = fp8_byte_f32_2((int)q0); s8 = fmaf(f, f, s8);
      f = fp8_byte_f32_3((int)q0); s8 = fmaf(f, f, s8);
      f = fp8_byte_f32_0((int)q1); s8 = fmaf(f, f, s8);
      f = fp8_byte_f32_1((int)q1); s8 = fmaf(f, f, s8);
      f = fp8_byte_f32_2((int)q1); s8 = fmaf(f, f, s8);
      f = fp8_byte_f32_3((int)q1); s8 = fmaf(f, f, s8);
    }
    unsigned qw[4] = {qb.x, qb.y, qb.z, qb.w};
#pragma unroll
    for (int i = 0; i < 4; ++i) {
      float g0 = bf2f(qw[i] & 0xffffu), g1 = bf2f(qw[i] >> 16);
      sb = fmaf(g0, g0, sb);
      sb = fmaf(g1, g1, sb);
    }
#pragma unroll
    for (int msk = 1; msk < 64; msk <<= 1) {
      s8 += __shfl_xor(s8, msk, 64);
      sb += __shfl_xor(sb, msk, 64);
    }
    if (l == 0) {
      b2[row - NTOK] = s8;
      b2b[row - NTOK] = sb;
    }
  }
}

// ---------------- distance GEMM (fp8 MX MFMA) + per-chunk argmin -------------
// EXACT round-1 structure (measured 57.8us, VGPR 92, 5 blk/CU): single 32KB
// buffer, 2 barriers/iter, XOR-slot LDS argmin table. launch_bounds(256,5)
// guards the 5-blocks/CU occupancy (non-binding at 92 VGPR; cap ~102).
__global__ __launch_bounds__(256, 5)
void k_dist(const u8* __restrict__ Qf, const float* __restrict__ b2,
            unsigned* __restrict__ part) {
  __shared__ __align__(16) u8 S[2][128 * 128];   // As, Bs: 16 KB each
  u8* As = S[0];
  u8* Bs = S[1];
  const int t = threadIdx.x;
  const int wave = t >> 6, lane = t & 63;
  const int v0 = blockIdx.x * 128;
  const int n0 = blockIdx.y * 128;
  const u8* Ga = Qf + (size_t)n0 * 512;
  const u8* Gb = Qf + (size_t)(NTOK + v0) * 512;

  // staging: wave w, instr p covers rows w*32+p*8 .. +8 (8 rows x 128B = 1KB)
  const int srow8 = lane >> 3;   // 0..7
  const int sslot = lane & 7;    // 16B slot within 128B row
  size_t go[4];
  u8 *lwA[4], *lwB[4];
#pragma unroll
  for (int p = 0; p < 4; ++p) {
    const int r = wave * 32 + p * 8 + srow8;
    go[p] = (size_t)r * 512 + (size_t)((sslot ^ (r & 7)) << 4);
    lwA[p] = As + (wave * 32 + p * 8) * 128;
    lwB[p] = Bs + (wave * 32 + p * 8) * 128;
  }

  const int wm = wave >> 1, wn = wave & 1;
  const int m = lane & 15, q = lane >> 4;
  // fragment k-range: lane group q covers k in [q*32, q*32+32) -> slots 2q,2q+1
  int roffA[4][2], roffB[4][2];
#pragma unroll
  for (int i = 0; i < 4; ++i) {
    int fr = wm * 64 + i * 16 + m;
    roffA[i][0] = fr * 128 + (((2 * q) ^ (fr & 7)) << 4);
    roffA[i][1] = fr * 128 + (((2 * q + 1) ^ (fr & 7)) << 4);
    fr = wn * 64 + i * 16 + m;
    roffB[i][0] = fr * 128 + (((2 * q) ^ (fr & 7)) << 4);
    roffB[i][1] = fr * 128 + (((2 * q + 1) ^ (fr & 7)) << 4);
  }

  f32x4 acc[4][4];
#pragma unroll
  for (int i = 0; i < 4; ++i)
#pragma unroll
    for (int j = 0; j < 4; ++j) acc[i][j] = (f32x4)(0.f);

  for (int it = 0; it < 4; ++it) {
    const int k0 = it * 128;
    __syncthreads();
#pragma unroll
    for (int p = 0; p < 4; ++p) gload_lds16(Ga + go[p] + k0, lwA[p]);
#pragma unroll
    for (int p = 0; p < 4; ++p) gload_lds16(Gb + go[p] + k0, lwB[p]);
    __syncthreads();
    i32x8 av[4], bv[4];
#pragma unroll
    for (int i = 0; i < 4; ++i) {
      uint4 lo = *(const uint4*)(As + roffA[i][0]);
      uint4 hi = *(const uint4*)(As + roffA[i][1]);
      av[i][0] = (int)lo.x; av[i][1] = (int)lo.y;
      av[i][2] = (int)lo.z; av[i][3] = (int)lo.w;
      av[i][4] = (int)hi.x; av[i][5] = (int)hi.y;
      av[i][6] = (int)hi.z; av[i][7] = (int)hi.w;
    }
#pragma unroll
    for (int j = 0; j < 4; ++j) {
      uint4 lo = *(const uint4*)(Bs + roffB[j][0]);
      uint4 hi = *(const uint4*)(Bs + roffB[j][1]);
      bv[j][0] = (int)lo.x; bv[j][1] = (int)lo.y;
      bv[j][2] = (int)lo.z; bv[j][3] = (int)lo.w;
      bv[j][4] = (int)hi.x; bv[j][5] = (int)hi.y;
      bv[j][6] = (int)hi.z; bv[j][7] = (int)hi.w;
    }
#pragma unroll
    for (int i = 0; i < 4; ++i)
#pragma unroll
      for (int j = 0; j < 4; ++j)
        acc[i][j] = mfma_mx(av[i], bv[j], acc[i][j]);
  }

  float b2v[4];
#pragma unroll
  for (int j = 0; j < 4; ++j) b2v[j] = b2[v0 + wn * 64 + j * 16 + m];

  __syncthreads();
  unsigned* tbl = (unsigned*)S;
#pragma unroll
  for (int i = 0; i < 4; ++i)
#pragma unroll
    for (int reg = 0; reg < 4; ++reg) {
      unsigned best = 0xFFFFFFFFu;
#pragma unroll
      for (int j = 0; j < 4; ++j) {
        float key = fmaf(-2.f, acc[i][j][reg], b2v[j]);
        unsigned pk = (key_of(key) & 0xFFFFE000u) |
                      (unsigned)(v0 + wn * 64 + j * 16 + m);
        best = (pk < best) ? pk : best;
      }
      int r = wm * 64 + i * 16 + q * 4 + reg;
      int slot = (wn * 16 + m) ^ ((r & 7) << 2);
      tbl[r * 32 + slot] = best;
    }
  __syncthreads();
  if (t < 128) {
    unsigned mn = 0xFFFFFFFFu;
#pragma unroll
    for (int cc = 0; cc < 8; ++cc) {
      int gc = (cc + t) & 7;
      int base = t * 32 + ((gc * 4) ^ ((t & 7) << 2));
      uint4 v = *(const uint4*)&tbl[base];
      unsigned a = (v.x < v.y) ? v.x : v.y;
      unsigned b = (v.z < v.w) ? v.z : v.w;
      a = (a < b) ? a : b;
      mn = (a < mn) ? a : mn;
    }
    part[(size_t)(n0 + t) * 64 + blockIdx.x] = mn;
  }
}

// -- gather + top-8 select + bf16 rescore + hist + loss partials --
__global__ __launch_bounds__(256)
void k_gather(const unsigned* __restrict__ part, const float* __restrict__ cb,
              const float* __restrict__ x, const ushort_t* __restrict__ P,
              const ushort_t* __restrict__ Qb, const float* __restrict__ b2b,
              float* __restrict__ out, int* __restrict__ hist,
              float* __restrict__ partq, float* __restrict__ partl) {
  const int n = blockIdx.x;
  const int t = threadIdx.x;
  const int lane = t & 63, wid = t >> 6;
  __shared__ float qin[512];
  __shared__ unsigned cand[8];
  __shared__ unsigned wcand[8];
  __shared__ int sIdx;
  __shared__ float rq[4], rl[4];

  // stage Qin[n] (bf16 -> fp32) into LDS
  unsigned uq = ((const unsigned*)(Qb + (size_t)n * LDIM))[t];
  qin[2 * t] = bf2f(uq & 0xffffu);
  qin[2 * t + 1] = bf2f(uq >> 16);

  // wave 0: iterated min-extraction -> top-8 of the 64 chunk winners
  if (t < 64) {
    unsigned v = part[(size_t)n * 64 + t];
#pragma unroll
    for (int it = 0; it < 8; ++it) {
      unsigned mn = v;
#pragma unroll
      for (int msk = 1; msk < 64; msk <<= 1) {
        unsigned o = (unsigned)__shfl_xor((int)mn, msk, 64);
        mn = (o < mn) ? o : mn;
      }
      if (t == 0) cand[it] = mn;
      if (v == mn) v = 0xFFFFFFFFu;  // indices unique -> masks exactly one lane
    }
  }
  __syncthreads();

  // rescore candidate c with 32 lanes (fully-coalesced 1 KB row read)
  const int c = t >> 5, sl = t & 31;
  const int cidx = (int)(cand[c] & 0x1FFFu);
  const unsigned* crow =
      (const unsigned*)(Qb + (size_t)(NTOK + cidx) * LDIM) + sl * 8;
  uint4 va = *(const uint4*)(crow);
  uint4 vb = *(const uint4*)(crow + 4);
  const float* qs = &qin[sl * 16];
  float dot = 0.f;
  dot = fmaf(bf2f(va.x & 0xffffu), qs[0], dot);
  dot = fmaf(bf2f(va.x >> 16),     qs[1], dot);
  dot = fmaf(bf2f(va.y & 0xffffu), qs[2], dot);
  dot = fmaf(bf2f(va.y >> 16),     qs[3], dot);
  dot = fmaf(bf2f(va.z & 0xffffu), qs[4], dot);
  dot = fmaf(bf2f(va.z >> 16),     qs[5], dot);
  dot = fmaf(bf2f(va.w & 0xffffu), qs[6], dot);
  dot = fmaf(bf2f(va.w >> 16),     qs[7], dot);
  dot = fmaf(bf2f(vb.x & 0xffffu), qs[8], dot);
  dot = fmaf(bf2f(vb.x >> 16),     qs[9], dot);
  dot = fmaf(bf2f(vb.y & 0xffffu), qs[10], dot);
  dot = fmaf(bf2f(vb.y >> 16),     qs[11], dot);
  dot = fmaf(bf2f(vb.z & 0xffffu), qs[12], dot);
  dot = fmaf(bf2f(vb.z >> 16),     qs[13], dot);
  dot = fmaf(bf2f(vb.w & 0xffffu), qs[14], dot);
  dot = fmaf(bf2f(vb.w >> 16),     qs[15], dot);
#pragma unroll
  for (int msk = 1; msk < 32; msk <<= 1) dot += __shfl_xor(dot, msk, 32);
  if (sl == 0) {
    float key = fmaf(-2.f, dot, b2b[cidx]);
    wcand[c] = (key_of(key) & 0xFFFFE000u) | (unsigned)cidx;
  }
  __syncthreads();
  if (t == 0) {
    unsigned mm = wcand[0];
#pragma unroll
    for (int i = 1; i < 8; ++i) mm = (wcand[i] < mm) ? wcand[i] : mm;
    int iv = (int)(mm & 0x1FFFu);
    sIdx = iv;
    atomicAdd(&hist[iv], 1);
  }
  __syncthreads();
  const int iv = sIdx;

  float4 qv = *(const float4*)&cb[(size_t)iv * DDIM + t * 4];
  float4 xv = *(const float4*)&x[(size_t)n * DDIM + t * 4];
  *(float4*)&out[(size_t)n * DDIM + t * 4] = qv;
  float d0 = qv.x - xv.x, d1 = qv.y - xv.y, d2 = qv.z - xv.z, d3 = qv.w - xv.w;
  float sq = d0 * d0 + d1 * d1 + d2 * d2 + d3 * d3;
  unsigned lq = *(const unsigned*)&P[(size_t)(NTOK + iv) * LDIM + t * 2];
  unsigned lx = *(const unsigned*)&P[(size_t)n * LDIM + t * 2];
  float e0 = bf2f(lq & 0xffffu) - bf2f(lx & 0xffffu);
  float e1 = bf2f(lq >> 16) - bf2f(lx >> 16);
  float sl2 = e0 * e0 + e1 * e1;
#pragma unroll
  for (int o = 32; o > 0; o >>= 1) {
    sq += __shfl_down(sq, o, 64);
    sl2 += __shfl_down(sl2, o, 64);
  }
  if (lane == 0) { rq[wid] = sq; rl[wid] = sl2; }
  __syncthreads();
  if (t == 0) {
    partq[n] = rq[0] + rq[1] + rq[2] + rq[3];
    partl[n] = rl[0] + rl[1] + rl[2] + rl[3];
  }
}

// ---------------- finalize scalars ----------------
__global__ __launch_bounds__(1024)
void k_final(const int* __restrict__ hist, const float* __restrict__ partq,
             const float* __restrict__ partl, float* __restrict__ out) {
  const int t = threadIdx.x;
  const int lane = t & 63, wid = t >> 6;  // 16 waves
  float perp = 0.f, usedf = 0.f, sq = 0.f, sl = 0.f;
  for (int v = t; v < VCB; v += 1024) {
    int h = hist[v];
    usedf += (h > 0) ? 1.f : 0.f;
    float p = (float)h * (1.f / (float)NTOK);
    perp -= p * logf(p + 1e-10f);
  }
  for (int n = t; n < NTOK; n += 1024) {
    sq += partq[n];
    sl += partl[n];
  }
#pragma unroll
  for (int o = 32; o > 0; o >>= 1) {
    perp  += __shfl_down(perp, o, 64);
    usedf += __shfl_down(usedf, o, 64);
    sq    += __shfl_down(sq, o, 64);
    sl    += __shfl_down(sl, o, 64);
  }
  __shared__ float red[16][4];
  if (lane == 0) {
    red[wid][0] = perp; red[wid][1] = usedf; red[wid][2] = sq; red[wid][3] = sl;
  }
  __syncthreads();
  if (t == 0) {
    float Pp = 0.f, U = 0.f, SQ = 0.f, SL = 0.f;
    for (int w = 0; w < 16; ++w) {
      Pp += red[w][0]; U += red[w][1]; SQ += red[w][2]; SL += red[w][3];
    }
    float mseq = SQ / (float)((size_t)NTOK * DDIM);
    float msel = SL / (float)((size_t)NTOK * LDIM);
    float loss = 1.25f * mseq + 1.25f * msel + 0.1f * Pp;
    out[(size_t)NTOK * DDIM + 0] = loss;
    out[(size_t)NTOK * DDIM + 1] = expf(Pp);
    out[(size_t)NTOK * DDIM + 2] = U / (float)VCB;
  }
}

extern "C" void kernel_launch(void* const* d_in, const int* in_sizes, int n_in,
                              void* d_out, int out_size, void* d_ws, size_t ws_size,
                              hipStream_t stream) {
  const float* x  = (const float*)d_in[0];
  const float* cb = (const float*)d_in[1];
  const float* Wi = (const float*)d_in[2];
  const float* bi = (const float*)d_in[3];
  const float* Wc = (const float*)d_in[4];
  const float* bc = (const float*)d_in[5];
  float* out = (float*)d_out;
  char* ws = (char*)d_ws;
  ushort_t* Ab   = (ushort_t*)(ws + OFF_AB);
  ushort_t* Qb   = (ushort_t*)(ws + OFF_QB);   // aliases Ab (dead by then)
  ushort_t* P    = (ushort_t*)(ws + OFF_P);
  u8*       Qf   = (u8*)(ws + OFF_QF);
  ushort_t* Wt   = (ushort_t*)(ws + OFF_WT);
  float*    b2   = (float*)(ws + OFF_B2);
  float*    b2b  = (float*)(ws + OFF_B2B);
  unsigned* part = (unsigned*)(ws + OFF_PART);
  int*      hist = (int*)(ws + OFF_HIST);
  float*    partq = (float*)(ws + OFF_PARTQ);
  float*    partl = (float*)(ws + OFF_PARTL);

  hipLaunchKernelGGL(k_wt, dim3(DDIM / 32, LDIM / 32, 2), dim3(32, 8), 0,
                     stream, Wi, Wc, Wt, hist);
  hipLaunchKernelGGL(k_cast, dim3((MROWS * DDIM) / (256 * 8)), dim3(256), 0,
                     stream, x, cb, Ab);
  hipLaunchKernelGGL(k_latent, dim3(LDIM / 128, MROWS / 128), dim3(256), 0,
                     stream, Ab, Wt, bi, bc, P);
  hipLaunchKernelGGL(k_rownorm, dim3(MROWS / 4), dim3(256), 0, stream, P, Qf,
                     Qb, b2, b2b);
  hipLaunchKernelGGL(k_dist, dim3(VCB / 128, NTOK / 128), dim3(256), 0, stream,
                     Qf, b2, part);
  hipLaunchKernelGGL(k_gather, dim3(NTOK), dim3(256), 0, stream, part, cb, x,
                     P, Qb, b2b, out, hist, partq, partl);
  hipLaunchKernelGGL(k_final, dim3(1), dim3(1024), 0, stream, hist, partq,
                     partl, out);
}

// Round 6
// 243.195 us; speedup vs baseline: 1.6013x; 1.6013x over previous
//
#include <hip/hip_runtime.h>
#include <hip/hip_bf16.h>
#include <stdint.h>

#define NTOK 8192   // B*T
#define DDIM 1024
#define LDIM 512
#define VCB  8192
#define MROWS 16384 // NTOK + VCB

typedef unsigned long long u64;
typedef unsigned short ushort_t;
typedef unsigned char u8;
typedef float f32x4 __attribute__((ext_vector_type(4)));
typedef short s16x8 __attribute__((ext_vector_type(8)));
typedef int i32x8 __attribute__((ext_vector_type(8)));

// ---- workspace layout (bytes) ----
#define OFF_AB     0ull                                   // 33.5 MB
#define OFF_QB     0ull                                   // alias (16.8 MB)
#define OFF_P      ((u64)MROWS * DDIM * 2)                // 16.8 MB
#define OFF_QF     (OFF_P + (u64)MROWS * LDIM * 2)        // 8.4 MB fp8
#define OFF_WT     (OFF_QF + (u64)MROWS * 512)            // 2 MB
#define OFF_B2     (OFF_WT + (u64)2 * LDIM * DDIM * 2)    // VCB fp32 (fp8-consistent)
#define OFF_B2B    (OFF_B2 + (u64)VCB * 4)                // VCB fp32 (bf16-consistent)
#define OFF_PART   (OFF_B2B + (u64)VCB * 4)               // NTOK*64 u32 = 2 MB
#define OFF_HIST   (OFF_PART + (u64)NTOK * 64 * 4)        // VCB int
#define OFF_PARTQ  (OFF_HIST + (u64)VCB * 4)              // NTOK fp32
#define OFF_PARTL  (OFF_PARTQ + (u64)NTOK * 4)            // NTOK fp32

__device__ __forceinline__ unsigned key_of(float f) {
  unsigned u = __float_as_uint(f);
  return (u & 0x80000000u) ? ~u : (u | 0x80000000u);
}

__device__ __forceinline__ ushort_t f2bf(float f) {
  unsigned u = __float_as_uint(f);
  unsigned r = (u + 0x7fffu + ((u >> 16) & 1u)) >> 16;
  return (ushort_t)r;
}
__device__ __forceinline__ float bf2f(unsigned b) {
  return __uint_as_float(b << 16);
}
__device__ __forceinline__ unsigned pkbf(float a, float b) {
  __hip_bfloat162 h = __float22bfloat162_rn(make_float2(a, b));
  unsigned r;
  __builtin_memcpy(&r, &h, 4);
  return r;
}

__device__ __forceinline__ void gload_lds16(const void* g, void* l) {
  __builtin_amdgcn_global_load_lds(
      (const __attribute__((address_space(1))) unsigned int*)g,
      (__attribute__((address_space(3))) unsigned int*)l, 16, 0, 0);
}

__device__ __forceinline__ f32x4 mfma16(s16x8 a, s16x8 b, f32x4 c) {
  return __builtin_amdgcn_mfma_f32_16x16x32_bf16(a, b, c, 0, 0, 0);
}
// MX-scaled fp8 MFMA, K=128, unit scales (E8M0 127 -> 2^0). FMT 0 = OCP e4m3.
__device__ __forceinline__ f32x4 mfma_mx(i32x8 a, i32x8 b, f32x4 c) {
  return __builtin_amdgcn_mfma_scale_f32_16x16x128_f8f6f4(
      a, b, c, 0, 0, 0, 0x7f7f7f7f, 0, 0x7f7f7f7f);
}

// fp8 byte -> f32, byte index must be literal: explicit dispatch
__device__ __forceinline__ float fp8_byte_f32_0(int w) { return __builtin_amdgcn_cvt_f32_fp8(w, 0); }
__device__ __forceinline__ float fp8_byte_f32_1(int w) { return __builtin_amdgcn_cvt_f32_fp8(w, 1); }
__device__ __forceinline__ float fp8_byte_f32_2(int w) { return __builtin_amdgcn_cvt_f32_fp8(w, 2); }
__device__ __forceinline__ float fp8_byte_f32_3(int w) { return __builtin_amdgcn_cvt_f32_fp8(w, 3); }

// ------ W transpose + bf16 cast: Wt[n][k] = W[k][n]; hist init folded -------
__global__ __launch_bounds__(256)
void k_wt(const float* __restrict__ Wi, const float* __restrict__ Wc,
          ushort_t* __restrict__ Wt, int* __restrict__ hist) {
  __shared__ float tile[32][33];
  const int tx = threadIdx.x, ty = threadIdx.y;
  const int t = ty * 32 + tx;
  const int lb = blockIdx.z * 512 + blockIdx.y * 32 + blockIdx.x;
  if (lb < 32) hist[lb * 256 + t] = 0;
  const float* W = blockIdx.z ? Wc : Wi;
  ushort_t* O = Wt + (blockIdx.z ? (size_t)LDIM * DDIM : 0);
  const int k0 = blockIdx.x * 32, n0 = blockIdx.y * 32;
#pragma unroll
  for (int i = 0; i < 4; ++i)
    tile[ty * 4 + i][tx] = W[(size_t)(k0 + ty * 4 + i) * LDIM + n0 + tx];
  __syncthreads();
#pragma unroll
  for (int i = 0; i < 4; ++i)
    O[(size_t)(n0 + ty * 4 + i) * DDIM + k0 + tx] = f2bf(tile[tx][ty * 4 + i]);
}

// ---------------- cast [x; codebook] fp32 -> Ab bf16 ----------------
__global__ __launch_bounds__(256)
void k_cast(const float* __restrict__ x, const float* __restrict__ cb,
            ushort_t* __restrict__ Ab) {
  size_t i = ((size_t)blockIdx.x * 256 + threadIdx.x) * 8;
  const size_t half = (size_t)NTOK * DDIM;
  const float* src = (i < half) ? (x + i) : (cb + (i - half));
  float4 a = *(const float4*)src;
  float4 b = *(const float4*)(src + 4);
  uint4 o = make_uint4(pkbf(a.x, a.y), pkbf(a.z, a.w),
                       pkbf(b.x, b.y), pkbf(b.z, b.w));
  *(uint4*)&Ab[i] = o;
}

// -------- latent GEMM (MFMA, BK=64): P = Ab @ Wt^T + b --------
// 128x128 tile, 16 K-iters of 64 bf16 (128B rows). 8-slot XOR swizzle
// slot^(row&7), both-sides involution, linear gload_lds dest.
__global__ __launch_bounds__(256)
void k_latent(const ushort_t* __restrict__ Ab, const ushort_t* __restrict__ Wt,
              const float* __restrict__ bi, const float* __restrict__ bc,
              ushort_t* __restrict__ Pb) {
  __shared__ __align__(16) u8 As[128 * 128];   // 16 KB
  __shared__ __align__(16) u8 Bs[128 * 128];   // 16 KB
  const int t = threadIdx.x;
  const int wave = t >> 6, lane = t & 63;
  const int col0 = blockIdx.x * 128;   // L index
  const int m0 = blockIdx.y * 128;     // row index in [0, MROWS)
  const bool isCode = (m0 >= NTOK);
  const u8* A = (const u8*)(Ab + (size_t)m0 * DDIM);
  const u8* W = (const u8*)(Wt + (isCode ? (size_t)LDIM * DDIM : 0) +
                            (size_t)col0 * DDIM);
  const float* bias = isCode ? bc : bi;

  // staging: wave w, instr p covers rows w*32+p*8..+8 (8 rows x 128B = 1KB)
  const int srow8 = lane >> 3;   // 0..7
  const int sslot = lane & 7;    // 16B slot within 128B row
  size_t go[4];
  int lwo[4];
#pragma unroll
  for (int p = 0; p < 4; ++p) {
    const int r = wave * 32 + p * 8 + srow8;
    go[p] = (size_t)r * 2048 + (size_t)((sslot ^ (r & 7)) << 4);
    lwo[p] = (wave * 32 + p * 8) * 128;
  }

  const int wm = wave >> 1, wn = wave & 1;
  const int m = lane & 15, q = lane >> 4;
  // bf16 16x16x32 A-frag: lane group q holds k=q*8..q*8+7 (16B). With BK=64,
  // k-subtile s in {0,1} -> slot = s*4+q of the 128B row, swizzled ^(fr&7).
  int roffA[4][2], roffB[4][2];
#pragma unroll
  for (int i = 0; i < 4; ++i) {
#pragma unroll
    for (int s = 0; s < 2; ++s) {
      int fr = wm * 64 + i * 16 + m;
      roffA[i][s] = fr * 128 + (((s * 4 + q) ^ (fr & 7)) << 4);
      fr = wn * 64 + i * 16 + m;
      roffB[i][s] = fr * 128 + (((s * 4 + q) ^ (fr & 7)) << 4);
    }
  }

  f32x4 acc[4][4];
#pragma unroll
  for (int i = 0; i < 4; ++i)
#pragma unroll
    for (int j = 0; j < 4; ++j) acc[i][j] = (f32x4)(0.f);

  for (int it = 0; it < DDIM / 64; ++it) {
    const size_t kb = (size_t)it * 128;
    __syncthreads();
#pragma unroll
    for (int p = 0; p < 4; ++p) gload_lds16(A + go[p] + kb, As + lwo[p]);
#pragma unroll
    for (int p = 0; p < 4; ++p) gload_lds16(W + go[p] + kb, Bs + lwo[p]);
    __syncthreads();
    s16x8 af[4][2], bfr[4][2];
#pragma unroll
    for (int i = 0; i < 4; ++i) {
      af[i][0] = *(const s16x8*)(As + roffA[i][0]);
      af[i][1] = *(const s16x8*)(As + roffA[i][1]);
    }
#pragma unroll
    for (int j = 0; j < 4; ++j) {
      bfr[j][0] = *(const s16x8*)(Bs + roffB[j][0]);
      bfr[j][1] = *(const s16x8*)(Bs + roffB[j][1]);
    }
#pragma unroll
    for (int s = 0; s < 2; ++s)
#pragma unroll
      for (int i = 0; i < 4; ++i)
#pragma unroll
        for (int j = 0; j < 4; ++j)
          acc[i][j] = mfma16(af[i][s], bfr[j][s], acc[i][j]);
  }

  float bv[4];
#pragma unroll
  for (int j = 0; j < 4; ++j) bv[j] = bias[col0 + wn * 64 + j * 16 + m];
#pragma unroll
  for (int i = 0; i < 4; ++i)
#pragma unroll
    for (int j = 0; j < 4; ++j) {
      int col = col0 + wn * 64 + j * 16 + m;
#pragma unroll
      for (int reg = 0; reg < 4; ++reg) {
        int row = m0 + wm * 64 + i * 16 + q * 4 + reg;
        Pb[(size_t)row * LDIM + col] = f2bf(acc[i][j][reg] + bv[j]);
      }
    }
}

// ------ row normalize: one wave per row, no LDS, no barriers ------
// lane l covers k = l*8 .. l*8+7 (linear). Writes Qf fp8 (8B), Qb bf16 (16B).
__global__ __launch_bounds__(256)
void k_rownorm(const ushort_t* __restrict__ P, u8* __restrict__ Qf,
               ushort_t* __restrict__ Qb, float* __restrict__ b2,
               float* __restrict__ b2b) {
  const int row = blockIdx.x * 4 + (threadIdx.x >> 6);
  const int l = threadIdx.x & 63;
  const uint4 pv = *(const uint4*)(P + (size_t)row * LDIM + l * 8);
  float v[8];
  v[0] = bf2f(pv.x & 0xffffu); v[1] = bf2f(pv.x >> 16);
  v[2] = bf2f(pv.y & 0xffffu); v[3] = bf2f(pv.y >> 16);
  v[4] = bf2f(pv.z & 0xffffu); v[5] = bf2f(pv.z >> 16);
  v[6] = bf2f(pv.w & 0xffffu); v[7] = bf2f(pv.w >> 16);
  float s = 0.f;
#pragma unroll
  for (int k = 0; k < 8; ++k) s = fmaf(v[k], v[k], s);
#pragma unroll
  for (int msk = 1; msk < 64; msk <<= 1) s += __shfl_xor(s, msk, 64);
  const float rs = (float)(1.0 / sqrt((double)s + 1e-12));
  float w[8];
#pragma unroll
  for (int k = 0; k < 8; ++k) w[k] = v[k] * rs;
  unsigned q0 = (unsigned)__builtin_amdgcn_cvt_pk_fp8_f32(w[0], w[1], 0, false);
  q0 = (unsigned)__builtin_amdgcn_cvt_pk_fp8_f32(w[2], w[3], (int)q0, true);
  unsigned q1 = (unsigned)__builtin_amdgcn_cvt_pk_fp8_f32(w[4], w[5], 0, false);
  q1 = (unsigned)__builtin_amdgcn_cvt_pk_fp8_f32(w[6], w[7], (int)q1, true);
  *(uint2*)(Qf + (size_t)row * 512 + l * 8) = make_uint2(q0, q1);
  uint4 qb = make_uint4(pkbf(w[0], w[1]), pkbf(w[2], w[3]),
                        pkbf(w[4], w[5]), pkbf(w[6], w[7]));
  *(uint4*)(Qb + (size_t)row * LDIM + l * 8) = qb;
  if (row >= NTOK) {
    float s8 = 0.f, sb = 0.f;
    {
      float f;
      f = fp8_byte_f32_0((int)q0); s8 = fmaf(f, f, s8);
      f = fp8_byte_f32_1((int)q0); s8 = fmaf(f, f, s8);
      f = fp8_byte_f32_2((int)q0); s8 = fmaf(f, f, s8);
      f = fp8_byte_f32_3((int)q0); s8 = fmaf(f, f, s8);
      f = fp8_byte_f32_0((int)q1); s8 = fmaf(f, f, s8);
      f = fp8_byte_f32_1((int)q1); s8 = fmaf(f, f, s8);
      f = fp8_byte_f32_2((int)q1); s8 = fmaf(f, f, s8);
      f = fp8_byte_f32_3((int)q1); s8 = fmaf(f, f, s8);
    }
    unsigned qw[4] = {qb.x, qb.y, qb.z, qb.w};
#pragma unroll
    for (int i = 0; i < 4; ++i) {
      float g0 = bf2f(qw[i] & 0xffffu), g1 = bf2f(qw[i] >> 16);
      sb = fmaf(g0, g0, sb);
      sb = fmaf(g1, g1, sb);
    }
#pragma unroll
    for (int msk = 1; msk < 64; msk <<= 1) {
      s8 += __shfl_xor(s8, msk, 64);
      sb += __shfl_xor(sb, msk, 64);
    }
    if (l == 0) {
      b2[row - NTOK] = s8;
      b2b[row - NTOK] = sb;
    }
  }
}

// ---------------- distance GEMM (fp8 MX MFMA) + per-chunk argmin -------------
// EXACT round-1 structure (measured 57.8us, VGPR 92, 5 blk/CU): single 32KB
// buffer, 2 barriers/iter, XOR-slot LDS argmin table. NO launch_bounds floor
// (round-5 lesson: forcing waves/EU made the allocator spill the accumulator
// to scratch -> ~1GB/dispatch HBM traffic, 4x slower).
__global__ __launch_bounds__(256)
void k_dist(const u8* __restrict__ Qf, const float* __restrict__ b2,
            unsigned* __restrict__ part) {
  __shared__ __align__(16) u8 S[2][128 * 128];   // As, Bs: 16 KB each
  u8* As = S[0];
  u8* Bs = S[1];
  const int t = threadIdx.x;
  const int wave = t >> 6, lane = t & 63;
  const int v0 = blockIdx.x * 128;
  const int n0 = blockIdx.y * 128;
  const u8* Ga = Qf + (size_t)n0 * 512;
  const u8* Gb = Qf + (size_t)(NTOK + v0) * 512;

  // staging: wave w, instr p covers rows w*32+p*8 .. +8 (8 rows x 128B = 1KB)
  const int srow8 = lane >> 3;   // 0..7
  const int sslot = lane & 7;    // 16B slot within 128B row
  size_t go[4];
  u8 *lwA[4], *lwB[4];
#pragma unroll
  for (int p = 0; p < 4; ++p) {
    const int r = wave * 32 + p * 8 + srow8;
    go[p] = (size_t)r * 512 + (size_t)((sslot ^ (r & 7)) << 4);
    lwA[p] = As + (wave * 32 + p * 8) * 128;
    lwB[p] = Bs + (wave * 32 + p * 8) * 128;
  }

  const int wm = wave >> 1, wn = wave & 1;
  const int m = lane & 15, q = lane >> 4;
  // fragment k-range: lane group q covers k in [q*32, q*32+32) -> slots 2q,2q+1
  int roffA[4][2], roffB[4][2];
#pragma unroll
  for (int i = 0; i < 4; ++i) {
    int fr = wm * 64 + i * 16 + m;
    roffA[i][0] = fr * 128 + (((2 * q) ^ (fr & 7)) << 4);
    roffA[i][1] = fr * 128 + (((2 * q + 1) ^ (fr & 7)) << 4);
    fr = wn * 64 + i * 16 + m;
    roffB[i][0] = fr * 128 + (((2 * q) ^ (fr & 7)) << 4);
    roffB[i][1] = fr * 128 + (((2 * q + 1) ^ (fr & 7)) << 4);
  }

  f32x4 acc[4][4];
#pragma unroll
  for (int i = 0; i < 4; ++i)
#pragma unroll
    for (int j = 0; j < 4; ++j) acc[i][j] = (f32x4)(0.f);

  for (int it = 0; it < 4; ++it) {
    const int k0 = it * 128;
    __syncthreads();
#pragma unroll
    for (int p = 0; p < 4; ++p) gload_lds16(Ga + go[p] + k0, lwA[p]);
#pragma unroll
    for (int p = 0; p < 4; ++p) gload_lds16(Gb + go[p] + k0, lwB[p]);
    __syncthreads();
    i32x8 av[4], bv[4];
#pragma unroll
    for (int i = 0; i < 4; ++i) {
      uint4 lo = *(const uint4*)(As + roffA[i][0]);
      uint4 hi = *(const uint4*)(As + roffA[i][1]);
      av[i][0] = (int)lo.x; av[i][1] = (int)lo.y;
      av[i][2] = (int)lo.z; av[i][3] = (int)lo.w;
      av[i][4] = (int)hi.x; av[i][5] = (int)hi.y;
      av[i][6] = (int)hi.z; av[i][7] = (int)hi.w;
    }
#pragma unroll
    for (int j = 0; j < 4; ++j) {
      uint4 lo = *(const uint4*)(Bs + roffB[j][0]);
      uint4 hi = *(const uint4*)(Bs + roffB[j][1]);
      bv[j][0] = (int)lo.x; bv[j][1] = (int)lo.y;
      bv[j][2] = (int)lo.z; bv[j][3] = (int)lo.w;
      bv[j][4] = (int)hi.x; bv[j][5] = (int)hi.y;
      bv[j][6] = (int)hi.z; bv[j][7] = (int)hi.w;
    }
#pragma unroll
    for (int i = 0; i < 4; ++i)
#pragma unroll
      for (int j = 0; j < 4; ++j)
        acc[i][j] = mfma_mx(av[i], bv[j], acc[i][j]);
  }

  float b2v[4];
#pragma unroll
  for (int j = 0; j < 4; ++j) b2v[j] = b2[v0 + wn * 64 + j * 16 + m];

  __syncthreads();
  unsigned* tbl = (unsigned*)S;
#pragma unroll
  for (int i = 0; i < 4; ++i)
#pragma unroll
    for (int reg = 0; reg < 4; ++reg) {
      unsigned best = 0xFFFFFFFFu;
#pragma unroll
      for (int j = 0; j < 4; ++j) {
        float key = fmaf(-2.f, acc[i][j][reg], b2v[j]);
        unsigned pk = (key_of(key) & 0xFFFFE000u) |
                      (unsigned)(v0 + wn * 64 + j * 16 + m);
        best = (pk < best) ? pk : best;
      }
      int r = wm * 64 + i * 16 + q * 4 + reg;
      int slot = (wn * 16 + m) ^ ((r & 7) << 2);
      tbl[r * 32 + slot] = best;
    }
  __syncthreads();
  if (t < 128) {
    unsigned mn = 0xFFFFFFFFu;
#pragma unroll
    for (int cc = 0; cc < 8; ++cc) {
      int gc = (cc + t) & 7;
      int base = t * 32 + ((gc * 4) ^ ((t & 7) << 2));
      uint4 v = *(const uint4*)&tbl[base];
      unsigned a = (v.x < v.y) ? v.x : v.y;
      unsigned b = (v.z < v.w) ? v.z : v.w;
      a = (a < b) ? a : b;
      mn = (a < mn) ? a : mn;
    }
    part[(size_t)(n0 + t) * 64 + blockIdx.x] = mn;
  }
}

// -- gather + top-8 select + bf16 rescore + hist + loss partials --
__global__ __launch_bounds__(256)
void k_gather(const unsigned* __restrict__ part, const float* __restrict__ cb,
              const float* __restrict__ x, const ushort_t* __restrict__ P,
              const ushort_t* __restrict__ Qb, const float* __restrict__ b2b,
              float* __restrict__ out, int* __restrict__ hist,
              float* __restrict__ partq, float* __restrict__ partl) {
  const int n = blockIdx.x;
  const int t = threadIdx.x;
  const int lane = t & 63, wid = t >> 6;
  __shared__ float qin[512];
  __shared__ unsigned cand[8];
  __shared__ unsigned wcand[8];
  __shared__ int sIdx;
  __shared__ float rq[4], rl[4];

  // stage Qin[n] (bf16 -> fp32) into LDS
  unsigned uq = ((const unsigned*)(Qb + (size_t)n * LDIM))[t];
  qin[2 * t] = bf2f(uq & 0xffffu);
  qin[2 * t + 1] = bf2f(uq >> 16);

  // wave 0: iterated min-extraction -> top-8 of the 64 chunk winners
  if (t < 64) {
    unsigned v = part[(size_t)n * 64 + t];
#pragma unroll
    for (int it = 0; it < 8; ++it) {
      unsigned mn = v;
#pragma unroll
      for (int msk = 1; msk < 64; msk <<= 1) {
        unsigned o = (unsigned)__shfl_xor((int)mn, msk, 64);
        mn = (o < mn) ? o : mn;
      }
      if (t == 0) cand[it] = mn;
      if (v == mn) v = 0xFFFFFFFFu;  // indices unique -> masks exactly one lane
    }
  }
  __syncthreads();

  // rescore candidate c with 32 lanes (fully-coalesced 1 KB row read)
  const int c = t >> 5, sl = t & 31;
  const int cidx = (int)(cand[c] & 0x1FFFu);
  const unsigned* crow =
      (const unsigned*)(Qb + (size_t)(NTOK + cidx) * LDIM) + sl * 8;
  uint4 va = *(const uint4*)(crow);
  uint4 vb = *(const uint4*)(crow + 4);
  const float* qs = &qin[sl * 16];
  float dot = 0.f;
  dot = fmaf(bf2f(va.x & 0xffffu), qs[0], dot);
  dot = fmaf(bf2f(va.x >> 16),     qs[1], dot);
  dot = fmaf(bf2f(va.y & 0xffffu), qs[2], dot);
  dot = fmaf(bf2f(va.y >> 16),     qs[3], dot);
  dot = fmaf(bf2f(va.z & 0xffffu), qs[4], dot);
  dot = fmaf(bf2f(va.z >> 16),     qs[5], dot);
  dot = fmaf(bf2f(va.w & 0xffffu), qs[6], dot);
  dot = fmaf(bf2f(va.w >> 16),     qs[7], dot);
  dot = fmaf(bf2f(vb.x & 0xffffu), qs[8], dot);
  dot = fmaf(bf2f(vb.x >> 16),     qs[9], dot);
  dot = fmaf(bf2f(vb.y & 0xffffu), qs[10], dot);
  dot = fmaf(bf2f(vb.y >> 16),     qs[11], dot);
  dot = fmaf(bf2f(vb.z & 0xffffu), qs[12], dot);
  dot = fmaf(bf2f(vb.z >> 16),     qs[13], dot);
  dot = fmaf(bf2f(vb.w & 0xffffu), qs[14], dot);
  dot = fmaf(bf2f(vb.w >> 16),     qs[15], dot);
#pragma unroll
  for (int msk = 1; msk < 32; msk <<= 1) dot += __shfl_xor(dot, msk, 32);
  if (sl == 0) {
    float key = fmaf(-2.f, dot, b2b[cidx]);
    wcand[c] = (key_of(key) & 0xFFFFE000u) | (unsigned)cidx;
  }
  __syncthreads();
  if (t == 0) {
    unsigned mm = wcand[0];
#pragma unroll
    for (int i = 1; i < 8; ++i) mm = (wcand[i] < mm) ? wcand[i] : mm;
    int iv = (int)(mm & 0x1FFFu);
    sIdx = iv;
    atomicAdd(&hist[iv], 1);
  }
  __syncthreads();
  const int iv = sIdx;

  float4 qv = *(const float4*)&cb[(size_t)iv * DDIM + t * 4];
  float4 xv = *(const float4*)&x[(size_t)n * DDIM + t * 4];
  *(float4*)&out[(size_t)n * DDIM + t * 4] = qv;
  float d0 = qv.x - xv.x, d1 = qv.y - xv.y, d2 = qv.z - xv.z, d3 = qv.w - xv.w;
  float sq = d0 * d0 + d1 * d1 + d2 * d2 + d3 * d3;
  unsigned lq = *(const unsigned*)&P[(size_t)(NTOK + iv) * LDIM + t * 2];
  unsigned lx = *(const unsigned*)&P[(size_t)n * LDIM + t * 2];
  float e0 = bf2f(lq & 0xffffu) - bf2f(lx & 0xffffu);
  float e1 = bf2f(lq >> 16) - bf2f(lx >> 16);
  float sl2 = e0 * e0 + e1 * e1;
#pragma unroll
  for (int o = 32; o > 0; o >>= 1) {
    sq += __shfl_down(sq, o, 64);
    sl2 += __shfl_down(sl2, o, 64);
  }
  if (lane == 0) { rq[wid] = sq; rl[wid] = sl2; }
  __syncthreads();
  if (t == 0) {
    partq[n] = rq[0] + rq[1] + rq[2] + rq[3];
    partl[n] = rl[0] + rl[1] + rl[2] + rl[3];
  }
}

// ---------------- finalize scalars ----------------
__global__ __launch_bounds__(1024)
void k_final(const int* __restrict__ hist, const float* __restrict__ partq,
             const float* __restrict__ partl, float* __restrict__ out) {
  const int t = threadIdx.x;
  const int lane = t & 63, wid = t >> 6;  // 16 waves
  float perp = 0.f, usedf = 0.f, sq = 0.f, sl = 0.f;
  for (int v = t; v < VCB; v += 1024) {
    int h = hist[v];
    usedf += (h > 0) ? 1.f : 0.f;
    float p = (float)h * (1.f / (float)NTOK);
    perp -= p * logf(p + 1e-10f);
  }
  for (int n = t; n < NTOK; n += 1024) {
    sq += partq[n];
    sl += partl[n];
  }
#pragma unroll
  for (int o = 32; o > 0; o >>= 1) {
    perp  += __shfl_down(perp, o, 64);
    usedf += __shfl_down(usedf, o, 64);
    sq    += __shfl_down(sq, o, 64);
    sl    += __shfl_down(sl, o, 64);
  }
  __shared__ float red[16][4];
  if (lane == 0) {
    red[wid][0] = perp; red[wid][1] = usedf; red[wid][2] = sq; red[wid][3] = sl;
  }
  __syncthreads();
  if (t == 0) {
    float Pp = 0.f, U = 0.f, SQ = 0.f, SL = 0.f;
    for (int w = 0; w < 16; ++w) {
      Pp += red[w][0]; U += red[w][1]; SQ += red[w][2]; SL += red[w][3];
    }
    float mseq = SQ / (float)((size_t)NTOK * DDIM);
    float msel = SL / (float)((size_t)NTOK * LDIM);
    float loss = 1.25f * mseq + 1.25f * msel + 0.1f * Pp;
    out[(size_t)NTOK * DDIM + 0] = loss;
    out[(size_t)NTOK * DDIM + 1] = expf(Pp);
    out[(size_t)NTOK * DDIM + 2] = U / (float)VCB;
  }
}

extern "C" void kernel_launch(void* const* d_in, const int* in_sizes, int n_in,
                              void* d_out, int out_size, void* d_ws, size_t ws_size,
                              hipStream_t stream) {
  const float* x  = (const float*)d_in[0];
  const float* cb = (const float*)d_in[1];
  const float* Wi = (const float*)d_in[2];
  const float* bi = (const float*)d_in[3];
  const float* Wc = (const float*)d_in[4];
  const float* bc = (const float*)d_in[5];
  float* out = (float*)d_out;
  char* ws = (char*)d_ws;
  ushort_t* Ab   = (ushort_t*)(ws + OFF_AB);
  ushort_t* Qb   = (ushort_t*)(ws + OFF_QB);   // aliases Ab (dead by then)
  ushort_t* P    = (ushort_t*)(ws + OFF_P);
  u8*       Qf   = (u8*)(ws + OFF_QF);
  ushort_t* Wt   = (ushort_t*)(ws + OFF_WT);
  float*    b2   = (float*)(ws + OFF_B2);
  float*    b2b  = (float*)(ws + OFF_B2B);
  unsigned* part = (unsigned*)(ws + OFF_PART);
  int*      hist = (int*)(ws + OFF_HIST);
  float*    partq = (float*)(ws + OFF_PARTQ);
  float*    partl = (float*)(ws + OFF_PARTL);

  hipLaunchKernelGGL(k_wt, dim3(DDIM / 32, LDIM / 32, 2), dim3(32, 8), 0,
                     stream, Wi, Wc, Wt, hist);
  hipLaunchKernelGGL(k_cast, dim3((MROWS * DDIM) / (256 * 8)), dim3(256), 0,
                     stream, x, cb, Ab);
  hipLaunchKernelGGL(k_latent, dim3(LDIM / 128, MROWS / 128), dim3(256), 0,
                     stream, Ab, Wt, bi, bc, P);
  hipLaunchKernelGGL(k_rownorm, dim3(MROWS / 4), dim3(256), 0, stream, P, Qf,
                     Qb, b2, b2b);
  hipLaunchKernelGGL(k_dist, dim3(VCB / 128, NTOK / 128), dim3(256), 0, stream,
                     Qf, b2, part);
  hipLaunchKernelGGL(k_gather, dim3(NTOK), dim3(256), 0, stream, part, cb, x,
                     P, Qb, b2b, out, hist, partq, partl);
  hipLaunchKernelGGL(k_final, dim3(1), dim3(1024), 0, stream, hist, partq,
                     partl, out);
}

// Round 7
// 236.857 us; speedup vs baseline: 1.6442x; 1.0268x over previous
//
#include <hip/hip_runtime.h>
#include <hip/hip_bf16.h>
#include <stdint.h>

#define NTOK 8192   // B*T
#define DDIM 1024
#define LDIM 512
#define VCB  8192
#define MROWS 16384 // NTOK + VCB

typedef unsigned long long u64;
typedef unsigned short ushort_t;
typedef unsigned char u8;
typedef float f32x4 __attribute__((ext_vector_type(4)));
typedef short s16x8 __attribute__((ext_vector_type(8)));
typedef int i32x4 __attribute__((ext_vector_type(4)));
typedef int i32x8 __attribute__((ext_vector_type(8)));

// ---- workspace layout (bytes) ----
#define OFF_AB     0ull                                   // 33.5 MB
#define OFF_QB     0ull                                   // alias (16.8 MB)
#define OFF_P      ((u64)MROWS * DDIM * 2)                // 16.8 MB
#define OFF_QF     (OFF_P + (u64)MROWS * LDIM * 2)        // 8.4 MB fp8
#define OFF_WT     (OFF_QF + (u64)MROWS * 512)            // 2 MB
#define OFF_B2     (OFF_WT + (u64)2 * LDIM * DDIM * 2)    // VCB fp32 (fp8-consistent)
#define OFF_B2B    (OFF_B2 + (u64)VCB * 4)                // VCB fp32 (bf16-consistent)
#define OFF_PART   (OFF_B2B + (u64)VCB * 4)               // NTOK*64 u32 = 2 MB
#define OFF_HIST   (OFF_PART + (u64)NTOK * 64 * 4)        // VCB int
#define OFF_PARTQ  (OFF_HIST + (u64)VCB * 4)              // NTOK fp32
#define OFF_PARTL  (OFF_PARTQ + (u64)NTOK * 4)            // NTOK fp32

__device__ __forceinline__ unsigned key_of(float f) {
  unsigned u = __float_as_uint(f);
  return (u & 0x80000000u) ? ~u : (u | 0x80000000u);
}

__device__ __forceinline__ ushort_t f2bf(float f) {
  unsigned u = __float_as_uint(f);
  unsigned r = (u + 0x7fffu + ((u >> 16) & 1u)) >> 16;
  return (ushort_t)r;
}
__device__ __forceinline__ float bf2f(unsigned b) {
  return __uint_as_float(b << 16);
}
__device__ __forceinline__ unsigned pkbf(float a, float b) {
  __hip_bfloat162 h = __float22bfloat162_rn(make_float2(a, b));
  unsigned r;
  __builtin_memcpy(&r, &h, 4);
  return r;
}

__device__ __forceinline__ void gload_lds16(const void* g, void* l) {
  __builtin_amdgcn_global_load_lds(
      (const __attribute__((address_space(1))) unsigned int*)g,
      (__attribute__((address_space(3))) unsigned int*)l, 16, 0, 0);
}

__device__ __forceinline__ f32x4 mfma16(s16x8 a, s16x8 b, f32x4 c) {
  return __builtin_amdgcn_mfma_f32_16x16x32_bf16(a, b, c, 0, 0, 0);
}
// MX-scaled fp8 MFMA, K=128, unit scales (E8M0 127 -> 2^0). FMT 0 = OCP e4m3.
__device__ __forceinline__ f32x4 mfma_mx(i32x8 a, i32x8 b, f32x4 c) {
  return __builtin_amdgcn_mfma_scale_f32_16x16x128_f8f6f4(
      a, b, c, 0, 0, 0, 0x7f7f7f7f, 0, 0x7f7f7f7f);
}

// fp8 byte -> f32, byte index must be literal: explicit dispatch
__device__ __forceinline__ float fp8_byte_f32_0(int w) { return __builtin_amdgcn_cvt_f32_fp8(w, 0); }
__device__ __forceinline__ float fp8_byte_f32_1(int w) { return __builtin_amdgcn_cvt_f32_fp8(w, 1); }
__device__ __forceinline__ float fp8_byte_f32_2(int w) { return __builtin_amdgcn_cvt_f32_fp8(w, 2); }
__device__ __forceinline__ float fp8_byte_f32_3(int w) { return __builtin_amdgcn_cvt_f32_fp8(w, 3); }

// ------ W transpose + bf16 cast: Wt[n][k] = W[k][n]; hist init folded -------
__global__ __launch_bounds__(256)
void k_wt(const float* __restrict__ Wi, const float* __restrict__ Wc,
          ushort_t* __restrict__ Wt, int* __restrict__ hist) {
  __shared__ float tile[32][33];
  const int tx = threadIdx.x, ty = threadIdx.y;
  const int t = ty * 32 + tx;
  const int lb = blockIdx.z * 512 + blockIdx.y * 32 + blockIdx.x;
  if (lb < 32) hist[lb * 256 + t] = 0;
  const float* W = blockIdx.z ? Wc : Wi;
  ushort_t* O = Wt + (blockIdx.z ? (size_t)LDIM * DDIM : 0);
  const int k0 = blockIdx.x * 32, n0 = blockIdx.y * 32;
#pragma unroll
  for (int i = 0; i < 4; ++i)
    tile[ty * 4 + i][tx] = W[(size_t)(k0 + ty * 4 + i) * LDIM + n0 + tx];
  __syncthreads();
#pragma unroll
  for (int i = 0; i < 4; ++i)
    O[(size_t)(n0 + ty * 4 + i) * DDIM + k0 + tx] = f2bf(tile[tx][ty * 4 + i]);
}

// ---------------- cast [x; codebook] fp32 -> Ab bf16 ----------------
__global__ __launch_bounds__(256)
void k_cast(const float* __restrict__ x, const float* __restrict__ cb,
            ushort_t* __restrict__ Ab) {
  size_t i = ((size_t)blockIdx.x * 256 + threadIdx.x) * 8;
  const size_t half = (size_t)NTOK * DDIM;
  const float* src = (i < half) ? (x + i) : (cb + (i - half));
  float4 a = *(const float4*)src;
  float4 b = *(const float4*)(src + 4);
  uint4 o = make_uint4(pkbf(a.x, a.y), pkbf(a.z, a.w),
                       pkbf(b.x, b.y), pkbf(b.z, b.w));
  *(uint4*)&Ab[i] = o;
}

// -------- latent GEMM (MFMA, BK=64, 8 waves): P = Ab @ Wt^T + b --------
// 128x128 tile, 512 threads (8 waves, 2x4 wave grid: per-wave 64x32 output).
// 16 K-iters of 64 bf16 (128B rows), 8-slot XOR swizzle slot^(row&7).
// 8-wave blocks double occupancy vs 4-wave at the 512-block grid (2 blk/CU).
__global__ __launch_bounds__(512)
void k_latent(const ushort_t* __restrict__ Ab, const ushort_t* __restrict__ Wt,
              const float* __restrict__ bi, const float* __restrict__ bc,
              ushort_t* __restrict__ Pb) {
  __shared__ __align__(16) u8 As[128 * 128];   // 16 KB
  __shared__ __align__(16) u8 Bs[128 * 128];   // 16 KB
  const int t = threadIdx.x;
  const int wave = t >> 6, lane = t & 63;
  const int col0 = blockIdx.x * 128;   // L index
  const int m0 = blockIdx.y * 128;     // row index in [0, MROWS)
  const bool isCode = (m0 >= NTOK);
  const u8* A = (const u8*)(Ab + (size_t)m0 * DDIM);
  const u8* W = (const u8*)(Wt + (isCode ? (size_t)LDIM * DDIM : 0) +
                            (size_t)col0 * DDIM);
  const float* bias = isCode ? bc : bi;

  // staging: wave stages rows wave*16 .. +16 (2 instr x 8 rows x 128B)
  const int srow8 = lane >> 3;   // 0..7
  const int sslot = lane & 7;    // 16B slot within 128B row
  size_t go[2];
  int lwo[2];
#pragma unroll
  for (int p = 0; p < 2; ++p) {
    const int r = wave * 16 + p * 8 + srow8;
    go[p] = (size_t)r * 2048 + (size_t)((sslot ^ (r & 7)) << 4);
    lwo[p] = (wave * 16 + p * 8) * 128;
  }

  const int wm = wave >> 2, wn = wave & 3;   // 2x4 wave grid
  const int m = lane & 15, q = lane >> 4;
  // bf16 16x16x32 frag: lane group q holds k=q*8..+7 (16B). BK=64: subtile
  // s in {0,1} -> slot s*4+q, swizzled ^(fr&7).
  int roffA[4][2], roffB[2][2];
#pragma unroll
  for (int i = 0; i < 4; ++i)
#pragma unroll
    for (int s = 0; s < 2; ++s) {
      int fr = wm * 64 + i * 16 + m;
      roffA[i][s] = fr * 128 + (((s * 4 + q) ^ (fr & 7)) << 4);
    }
#pragma unroll
  for (int j = 0; j < 2; ++j)
#pragma unroll
    for (int s = 0; s < 2; ++s) {
      int fr = wn * 32 + j * 16 + m;
      roffB[j][s] = fr * 128 + (((s * 4 + q) ^ (fr & 7)) << 4);
    }

  f32x4 acc[4][2];
#pragma unroll
  for (int i = 0; i < 4; ++i)
#pragma unroll
    for (int j = 0; j < 2; ++j) acc[i][j] = (f32x4)(0.f);

  for (int it = 0; it < DDIM / 64; ++it) {
    const size_t kb = (size_t)it * 128;
    __syncthreads();
#pragma unroll
    for (int p = 0; p < 2; ++p) gload_lds16(A + go[p] + kb, As + lwo[p]);
#pragma unroll
    for (int p = 0; p < 2; ++p) gload_lds16(W + go[p] + kb, Bs + lwo[p]);
    __syncthreads();
    s16x8 af[4][2], bfr[2][2];
#pragma unroll
    for (int i = 0; i < 4; ++i) {
      af[i][0] = *(const s16x8*)(As + roffA[i][0]);
      af[i][1] = *(const s16x8*)(As + roffA[i][1]);
    }
#pragma unroll
    for (int j = 0; j < 2; ++j) {
      bfr[j][0] = *(const s16x8*)(Bs + roffB[j][0]);
      bfr[j][1] = *(const s16x8*)(Bs + roffB[j][1]);
    }
#pragma unroll
    for (int s = 0; s < 2; ++s)
#pragma unroll
      for (int i = 0; i < 4; ++i)
#pragma unroll
        for (int j = 0; j < 2; ++j)
          acc[i][j] = mfma16(af[i][s], bfr[j][s], acc[i][j]);
  }

  float bv[2];
#pragma unroll
  for (int j = 0; j < 2; ++j) bv[j] = bias[col0 + wn * 32 + j * 16 + m];
#pragma unroll
  for (int i = 0; i < 4; ++i)
#pragma unroll
    for (int j = 0; j < 2; ++j) {
      int col = col0 + wn * 32 + j * 16 + m;
#pragma unroll
      for (int reg = 0; reg < 4; ++reg) {
        int row = m0 + wm * 64 + i * 16 + q * 4 + reg;
        Pb[(size_t)row * LDIM + col] = f2bf(acc[i][j][reg] + bv[j]);
      }
    }
}

// ------ row normalize: one wave per row, no LDS, no barriers ------
__global__ __launch_bounds__(256)
void k_rownorm(const ushort_t* __restrict__ P, u8* __restrict__ Qf,
               ushort_t* __restrict__ Qb, float* __restrict__ b2,
               float* __restrict__ b2b) {
  const int row = blockIdx.x * 4 + (threadIdx.x >> 6);
  const int l = threadIdx.x & 63;
  const uint4 pv = *(const uint4*)(P + (size_t)row * LDIM + l * 8);
  float v[8];
  v[0] = bf2f(pv.x & 0xffffu); v[1] = bf2f(pv.x >> 16);
  v[2] = bf2f(pv.y & 0xffffu); v[3] = bf2f(pv.y >> 16);
  v[4] = bf2f(pv.z & 0xffffu); v[5] = bf2f(pv.z >> 16);
  v[6] = bf2f(pv.w & 0xffffu); v[7] = bf2f(pv.w >> 16);
  float s = 0.f;
#pragma unroll
  for (int k = 0; k < 8; ++k) s = fmaf(v[k], v[k], s);
#pragma unroll
  for (int msk = 1; msk < 64; msk <<= 1) s += __shfl_xor(s, msk, 64);
  const float rs = (float)(1.0 / sqrt((double)s + 1e-12));
  float w[8];
#pragma unroll
  for (int k = 0; k < 8; ++k) w[k] = v[k] * rs;
  unsigned q0 = (unsigned)__builtin_amdgcn_cvt_pk_fp8_f32(w[0], w[1], 0, false);
  q0 = (unsigned)__builtin_amdgcn_cvt_pk_fp8_f32(w[2], w[3], (int)q0, true);
  unsigned q1 = (unsigned)__builtin_amdgcn_cvt_pk_fp8_f32(w[4], w[5], 0, false);
  q1 = (unsigned)__builtin_amdgcn_cvt_pk_fp8_f32(w[6], w[7], (int)q1, true);
  *(uint2*)(Qf + (size_t)row * 512 + l * 8) = make_uint2(q0, q1);
  uint4 qb = make_uint4(pkbf(w[0], w[1]), pkbf(w[2], w[3]),
                        pkbf(w[4], w[5]), pkbf(w[6], w[7]));
  *(uint4*)(Qb + (size_t)row * LDIM + l * 8) = qb;
  if (row >= NTOK) {
    float s8 = 0.f, sb = 0.f;
    {
      float f;
      f = fp8_byte_f32_0((int)q0); s8 = fmaf(f, f, s8);
      f = fp8_byte_f32_1((int)q0); s8 = fmaf(f, f, s8);
      f = fp8_byte_f32_2((int)q0); s8 = fmaf(f, f, s8);
      f = fp8_byte_f32_3((int)q0); s8 = fmaf(f, f, s8);
      f = fp8_byte_f32_0((int)q1); s8 = fmaf(f, f, s8);
      f = fp8_byte_f32_1((int)q1); s8 = fmaf(f, f, s8);
      f = fp8_byte_f32_2((int)q1); s8 = fmaf(f, f, s8);
      f = fp8_byte_f32_3((int)q1); s8 = fmaf(f, f, s8);
    }
    unsigned qw[4] = {qb.x, qb.y, qb.z, qb.w};
#pragma unroll
    for (int i = 0; i < 4; ++i) {
      float g0 = bf2f(qw[i] & 0xffffu), g1 = bf2f(qw[i] >> 16);
      sb = fmaf(g0, g0, sb);
      sb = fmaf(g1, g1, sb);
    }
#pragma unroll
    for (int msk = 1; msk < 64; msk <<= 1) {
      s8 += __shfl_xor(s8, msk, 64);
      sb += __shfl_xor(sb, msk, 64);
    }
    if (l == 0) {
      b2[row - NTOK] = s8;
      b2b[row - NTOK] = sb;
    }
  }
}

// -------- distance GEMM (fp8 MX MFMA, 8 waves) + per-chunk argmin --------
// 128x128 tile, 512 threads (2x4 wave grid: per-wave 64x32 output, acc 32
// VGPR). Same 32KB LDS + staging swizzle as the verified 4-wave version;
// occupancy 20 -> 32 waves/CU (wave-cap bound: 4 blk x 8 waves). MFMA
// accumulation order per output unchanged -> bit-identical results.
__global__ __launch_bounds__(512)
void k_dist(const u8* __restrict__ Qf, const float* __restrict__ b2,
            unsigned* __restrict__ part) {
  __shared__ __align__(16) u8 S[2][128 * 128];   // As, Bs: 16 KB each
  u8* As = S[0];
  u8* Bs = S[1];
  const int t = threadIdx.x;
  const int wave = t >> 6, lane = t & 63;
  const int v0 = blockIdx.x * 128;
  const int n0 = blockIdx.y * 128;
  const u8* Ga = Qf + (size_t)n0 * 512;
  const u8* Gb = Qf + (size_t)(NTOK + v0) * 512;

  // staging: wave stages rows wave*16 .. +16 (2 instr x 8 rows x 128B)
  const int srow8 = lane >> 3;   // 0..7
  const int sslot = lane & 7;    // 16B slot within 128B row
  size_t go[2];
  int lwo[2];
#pragma unroll
  for (int p = 0; p < 2; ++p) {
    const int r = wave * 16 + p * 8 + srow8;
    go[p] = (size_t)r * 512 + (size_t)((sslot ^ (r & 7)) << 4);
    lwo[p] = (wave * 16 + p * 8) * 128;
  }

  const int wm = wave >> 2, wn = wave & 3;   // 2x4 wave grid
  const int m = lane & 15, q = lane >> 4;
  // fragment k-range: lane group q covers k in [q*32, q*32+32) -> slots 2q,2q+1
  int roffA[4][2], roffB[2][2];
#pragma unroll
  for (int i = 0; i < 4; ++i) {
    int fr = wm * 64 + i * 16 + m;
    roffA[i][0] = fr * 128 + (((2 * q) ^ (fr & 7)) << 4);
    roffA[i][1] = fr * 128 + (((2 * q + 1) ^ (fr & 7)) << 4);
  }
#pragma unroll
  for (int j = 0; j < 2; ++j) {
    int fr = wn * 32 + j * 16 + m;
    roffB[j][0] = fr * 128 + (((2 * q) ^ (fr & 7)) << 4);
    roffB[j][1] = fr * 128 + (((2 * q + 1) ^ (fr & 7)) << 4);
  }

  f32x4 acc[4][2];
#pragma unroll
  for (int i = 0; i < 4; ++i)
#pragma unroll
    for (int j = 0; j < 2; ++j) acc[i][j] = (f32x4)(0.f);

  for (int it = 0; it < 4; ++it) {
    const int k0 = it * 128;
    __syncthreads();
#pragma unroll
    for (int p = 0; p < 2; ++p) gload_lds16(Ga + go[p] + k0, As + lwo[p]);
#pragma unroll
    for (int p = 0; p < 2; ++p) gload_lds16(Gb + go[p] + k0, Bs + lwo[p]);
    __syncthreads();
    i32x8 av[4], bv[2];
#pragma unroll
    for (int i = 0; i < 4; ++i) {
      i32x4 lo = *(const i32x4*)(As + roffA[i][0]);
      i32x4 hi = *(const i32x4*)(As + roffA[i][1]);
      av[i] = __builtin_shufflevector(lo, hi, 0, 1, 2, 3, 4, 5, 6, 7);
    }
#pragma unroll
    for (int j = 0; j < 2; ++j) {
      i32x4 lo = *(const i32x4*)(Bs + roffB[j][0]);
      i32x4 hi = *(const i32x4*)(Bs + roffB[j][1]);
      bv[j] = __builtin_shufflevector(lo, hi, 0, 1, 2, 3, 4, 5, 6, 7);
    }
#pragma unroll
    for (int i = 0; i < 4; ++i)
#pragma unroll
      for (int j = 0; j < 2; ++j)
        acc[i][j] = mfma_mx(av[i], bv[j], acc[i][j]);
  }

  float b2v[2];
#pragma unroll
  for (int j = 0; j < 2; ++j) b2v[j] = b2[v0 + wn * 32 + j * 16 + m];

  // argmin: per (i,reg) min over 2 cols -> tbl[128 rows][64 slots] (32 KB,
  // exactly fills S). 4-way write/read conflicts, once per block: negligible.
  __syncthreads();
  unsigned* tbl = (unsigned*)S;
#pragma unroll
  for (int i = 0; i < 4; ++i)
#pragma unroll
    for (int reg = 0; reg < 4; ++reg) {
      unsigned best = 0xFFFFFFFFu;
#pragma unroll
      for (int j = 0; j < 2; ++j) {
        float key = fmaf(-2.f, acc[i][j][reg], b2v[j]);
        unsigned pk = (key_of(key) & 0xFFFFE000u) |
                      (unsigned)(v0 + wn * 32 + j * 16 + m);
        best = (pk < best) ? pk : best;
      }
      int r = wm * 64 + i * 16 + q * 4 + reg;
      tbl[r * 64 + wn * 16 + m] = best;
    }
  __syncthreads();
  if (t < 128) {
    unsigned mn = 0xFFFFFFFFu;
#pragma unroll
    for (int cc = 0; cc < 16; ++cc) {
      int base = t * 64 + ((cc + t) & 15) * 4;
      uint4 v = *(const uint4*)&tbl[base];
      unsigned a = (v.x < v.y) ? v.x : v.y;
      unsigned b = (v.z < v.w) ? v.z : v.w;
      a = (a < b) ? a : b;
      mn = (a < mn) ? a : mn;
    }
    part[(size_t)(n0 + t) * 64 + blockIdx.x] = mn;
  }
}

// -- gather + top-8 select + bf16 rescore + hist + loss partials --
__global__ __launch_bounds__(256)
void k_gather(const unsigned* __restrict__ part, const float* __restrict__ cb,
              const float* __restrict__ x, const ushort_t* __restrict__ P,
              const ushort_t* __restrict__ Qb, const float* __restrict__ b2b,
              float* __restrict__ out, int* __restrict__ hist,
              float* __restrict__ partq, float* __restrict__ partl) {
  const int n = blockIdx.x;
  const int t = threadIdx.x;
  const int lane = t & 63, wid = t >> 6;
  __shared__ float qin[512];
  __shared__ unsigned cand[8];
  __shared__ unsigned wcand[8];
  __shared__ int sIdx;
  __shared__ float rq[4], rl[4];

  // stage Qin[n] (bf16 -> fp32) into LDS
  unsigned uq = ((const unsigned*)(Qb + (size_t)n * LDIM))[t];
  qin[2 * t] = bf2f(uq & 0xffffu);
  qin[2 * t + 1] = bf2f(uq >> 16);

  // wave 0: iterated min-extraction -> top-8 of the 64 chunk winners
  if (t < 64) {
    unsigned v = part[(size_t)n * 64 + t];
#pragma unroll
    for (int it = 0; it < 8; ++it) {
      unsigned mn = v;
#pragma unroll
      for (int msk = 1; msk < 64; msk <<= 1) {
        unsigned o = (unsigned)__shfl_xor((int)mn, msk, 64);
        mn = (o < mn) ? o : mn;
      }
      if (t == 0) cand[it] = mn;
      if (v == mn) v = 0xFFFFFFFFu;  // indices unique -> masks exactly one lane
    }
  }
  __syncthreads();

  // rescore candidate c with 32 lanes (fully-coalesced 1 KB row read)
  const int c = t >> 5, sl = t & 31;
  const int cidx = (int)(cand[c] & 0x1FFFu);
  const unsigned* crow =
      (const unsigned*)(Qb + (size_t)(NTOK + cidx) * LDIM) + sl * 8;
  uint4 va = *(const uint4*)(crow);
  uint4 vb = *(const uint4*)(crow + 4);
  const float* qs = &qin[sl * 16];
  float dot = 0.f;
  dot = fmaf(bf2f(va.x & 0xffffu), qs[0], dot);
  dot = fmaf(bf2f(va.x >> 16),     qs[1], dot);
  dot = fmaf(bf2f(va.y & 0xffffu), qs[2], dot);
  dot = fmaf(bf2f(va.y >> 16),     qs[3], dot);
  dot = fmaf(bf2f(va.z & 0xffffu), qs[4], dot);
  dot = fmaf(bf2f(va.z >> 16),     qs[5], dot);
  dot = fmaf(bf2f(va.w & 0xffffu), qs[6], dot);
  dot = fmaf(bf2f(va.w >> 16),     qs[7], dot);
  dot = fmaf(bf2f(vb.x & 0xffffu), qs[8], dot);
  dot = fmaf(bf2f(vb.x >> 16),     qs[9], dot);
  dot = fmaf(bf2f(vb.y & 0xffffu), qs[10], dot);
  dot = fmaf(bf2f(vb.y >> 16),     qs[11], dot);
  dot = fmaf(bf2f(vb.z & 0xffffu), qs[12], dot);
  dot = fmaf(bf2f(vb.z >> 16),     qs[13], dot);
  dot = fmaf(bf2f(vb.w & 0xffffu), qs[14], dot);
  dot = fmaf(bf2f(vb.w >> 16),     qs[15], dot);
#pragma unroll
  for (int msk = 1; msk < 32; msk <<= 1) dot += __shfl_xor(dot, msk, 32);
  if (sl == 0) {
    float key = fmaf(-2.f, dot, b2b[cidx]);
    wcand[c] = (key_of(key) & 0xFFFFE000u) | (unsigned)cidx;
  }
  __syncthreads();
  if (t == 0) {
    unsigned mm = wcand[0];
#pragma unroll
    for (int i = 1; i < 8; ++i) mm = (wcand[i] < mm) ? wcand[i] : mm;
    int iv = (int)(mm & 0x1FFFu);
    sIdx = iv;
    atomicAdd(&hist[iv], 1);
  }
  __syncthreads();
  const int iv = sIdx;

  float4 qv = *(const float4*)&cb[(size_t)iv * DDIM + t * 4];
  float4 xv = *(const float4*)&x[(size_t)n * DDIM + t * 4];
  *(float4*)&out[(size_t)n * DDIM + t * 4] = qv;
  float d0 = qv.x - xv.x, d1 = qv.y - xv.y, d2 = qv.z - xv.z, d3 = qv.w - xv.w;
  float sq = d0 * d0 + d1 * d1 + d2 * d2 + d3 * d3;
  unsigned lq = *(const unsigned*)&P[(size_t)(NTOK + iv) * LDIM + t * 2];
  unsigned lx = *(const unsigned*)&P[(size_t)n * LDIM + t * 2];
  float e0 = bf2f(lq & 0xffffu) - bf2f(lx & 0xffffu);
  float e1 = bf2f(lq >> 16) - bf2f(lx >> 16);
  float sl2 = e0 * e0 + e1 * e1;
#pragma unroll
  for (int o = 32; o > 0; o >>= 1) {
    sq += __shfl_down(sq, o, 64);
    sl2 += __shfl_down(sl2, o, 64);
  }
  if (lane == 0) { rq[wid] = sq; rl[wid] = sl2; }
  __syncthreads();
  if (t == 0) {
    partq[n] = rq[0] + rq[1] + rq[2] + rq[3];
    partl[n] = rl[0] + rl[1] + rl[2] + rl[3];
  }
}

// ---------------- finalize scalars ----------------
__global__ __launch_bounds__(1024)
void k_final(const int* __restrict__ hist, const float* __restrict__ partq,
             const float* __restrict__ partl, float* __restrict__ out) {
  const int t = threadIdx.x;
  const int lane = t & 63, wid = t >> 6;  // 16 waves
  float perp = 0.f, usedf = 0.f, sq = 0.f, sl = 0.f;
  for (int v = t; v < VCB; v += 1024) {
    int h = hist[v];
    usedf += (h > 0) ? 1.f : 0.f;
    float p = (float)h * (1.f / (float)NTOK);
    perp -= p * logf(p + 1e-10f);
  }
  for (int n = t; n < NTOK; n += 1024) {
    sq += partq[n];
    sl += partl[n];
  }
#pragma unroll
  for (int o = 32; o > 0; o >>= 1) {
    perp  += __shfl_down(perp, o, 64);
    usedf += __shfl_down(usedf, o, 64);
    sq    += __shfl_down(sq, o, 64);
    sl    += __shfl_down(sl, o, 64);
  }
  __shared__ float red[16][4];
  if (lane == 0) {
    red[wid][0] = perp; red[wid][1] = usedf; red[wid][2] = sq; red[wid][3] = sl;
  }
  __syncthreads();
  if (t == 0) {
    float Pp = 0.f, U = 0.f, SQ = 0.f, SL = 0.f;
    for (int w = 0; w < 16; ++w) {
      Pp += red[w][0]; U += red[w][1]; SQ += red[w][2]; SL += red[w][3];
    }
    float mseq = SQ / (float)((size_t)NTOK * DDIM);
    float msel = SL / (float)((size_t)NTOK * LDIM);
    float loss = 1.25f * mseq + 1.25f * msel + 0.1f * Pp;
    out[(size_t)NTOK * DDIM + 0] = loss;
    out[(size_t)NTOK * DDIM + 1] = expf(Pp);
    out[(size_t)NTOK * DDIM + 2] = U / (float)VCB;
  }
}

extern "C" void kernel_launch(void* const* d_in, const int* in_sizes, int n_in,
                              void* d_out, int out_size, void* d_ws, size_t ws_size,
                              hipStream_t stream) {
  const float* x  = (const float*)d_in[0];
  const float* cb = (const float*)d_in[1];
  const float* Wi = (const float*)d_in[2];
  const float* bi = (const float*)d_in[3];
  const float* Wc = (const float*)d_in[4];
  const float* bc = (const float*)d_in[5];
  float* out = (float*)d_out;
  char* ws = (char*)d_ws;
  ushort_t* Ab   = (ushort_t*)(ws + OFF_AB);
  ushort_t* Qb   = (ushort_t*)(ws + OFF_QB);   // aliases Ab (dead by then)
  ushort_t* P    = (ushort_t*)(ws + OFF_P);
  u8*       Qf   = (u8*)(ws + OFF_QF);
  ushort_t* Wt   = (ushort_t*)(ws + OFF_WT);
  float*    b2   = (float*)(ws + OFF_B2);
  float*    b2b  = (float*)(ws + OFF_B2B);
  unsigned* part = (unsigned*)(ws + OFF_PART);
  int*      hist = (int*)(ws + OFF_HIST);
  float*    partq = (float*)(ws + OFF_PARTQ);
  float*    partl = (float*)(ws + OFF_PARTL);

  hipLaunchKernelGGL(k_wt, dim3(DDIM / 32, LDIM / 32, 2), dim3(32, 8), 0,
                     stream, Wi, Wc, Wt, hist);
  hipLaunchKernelGGL(k_cast, dim3((MROWS * DDIM) / (256 * 8)), dim3(256), 0,
                     stream, x, cb, Ab);
  hipLaunchKernelGGL(k_latent, dim3(LDIM / 128, MROWS / 128), dim3(512), 0,
                     stream, Ab, Wt, bi, bc, P);
  hipLaunchKernelGGL(k_rownorm, dim3(MROWS / 4), dim3(256), 0, stream, P, Qf,
                     Qb, b2, b2b);
  hipLaunchKernelGGL(k_dist, dim3(VCB / 128, NTOK / 128), dim3(512), 0, stream,
                     Qf, b2, part);
  hipLaunchKernelGGL(k_gather, dim3(NTOK), dim3(256), 0, stream, part, cb, x,
                     P, Qb, b2b, out, hist, partq, partl);
  hipLaunchKernelGGL(k_final, dim3(1), dim3(1024), 0, stream, hist, partq,
                     partl, out);
}